// Round 1
// baseline (325.638 us; speedup 1.0000x reference)
//
#include <hip/hip_runtime.h>
#include <hip/hip_fp8.h>

// Problem constants
constexpr int B = 8;
constexpr int N = 2048;
constexpr int D = 256;
constexpr int L = 2;
constexpr int M = B * N;   // 16384

typedef __bf16 bf16x8 __attribute__((ext_vector_type(8)));
typedef float  f32x4  __attribute__((ext_vector_type(4)));
typedef float  f32x16 __attribute__((ext_vector_type(16)));
typedef int    i32x4  __attribute__((ext_vector_type(4)));
typedef int    i32x8  __attribute__((ext_vector_type(8)));

static __device__ __forceinline__ unsigned short f2bf(float f) {
    union { float f; unsigned u; } v; v.f = f;
    unsigned r = v.u + 0x7fffu + ((v.u >> 16) & 1u);   // RNE
    return (unsigned short)(r >> 16);
}

static __device__ __forceinline__ unsigned char f2fp8(float f) {
    __hip_fp8_e4m3 v(f);          // OCP e4m3fn on gfx950
    return (unsigned char)v.__x;
}

static __device__ __forceinline__ void gload16(const void* g, void* l) {
    __builtin_amdgcn_global_load_lds(
        (__attribute__((address_space(1))) void*)(g),
        (__attribute__((address_space(3))) void*)(l),
        16, 0, 0);
}

// ---------------------------------------------------------------------------
// Kernel 1 (merged prep): three block-ranges.
//  [0,4096):       denom+cast: rowsum/rdenom, adj fp32 -> adj8 (e4m3)
//  [4096,5120):    nodes -> nodesbf (bf16 row-major) + nodesT8 (fp8 [b][d][n])
//  [5120,5248):    weights fp32 -> bf16 (both, all layers)
// ---------------------------------------------------------------------------
__global__ __launch_bounds__(256)
void prep_kernel(const float* __restrict__ adj,
                 const float* __restrict__ nodes,
                 const float* __restrict__ W0_w, const float* __restrict__ Wr_w,
                 unsigned char* __restrict__ adj8,
                 float* __restrict__ rdenom, float* __restrict__ rowsum,
                 unsigned short* __restrict__ nodesbf,
                 unsigned char* __restrict__ nodesT8,
                 unsigned short* __restrict__ W0b, unsigned short* __restrict__ Wrb) {
    __shared__ unsigned char T8[64][68];
    const int bx = blockIdx.x;
    const int t  = threadIdx.x;
    if (bx < 4096) {
        // ---- denom + adj cast: one wave per row ----
        const int wave = t >> 6;
        const int lane = t & 63;
        const int row  = bx * 4 + wave;              // [0, B*N)
        const float4* p = (const float4*)(adj + (size_t)row * N);
        uchar4* q = (uchar4*)(adj8 + (size_t)row * N);
        float s = 0.f;
        #pragma unroll
        for (int i = 0; i < 8; ++i) {
            float4 v = p[lane + i * 64];
            s += (v.x + v.y) + (v.z + v.w);
            uchar4 o;
            o.x = f2fp8(v.x); o.y = f2fp8(v.y); o.z = f2fp8(v.z); o.w = f2fp8(v.w);
            q[lane + i * 64] = o;
        }
        #pragma unroll
        for (int off = 32; off > 0; off >>= 1) s += __shfl_down(s, off);
        if (lane == 0) {
            rowsum[row] = s;
            rdenom[row] = 1.0f / (s + 1.0f);
        }
    } else if (bx < 4096 + 1024) {
        // ---- nodes cast + transpose: 64x64 tile ----
        const int idx = bx - 4096;                   // [0,1024)
        const int b   = idx >> 7;
        const int rem = idx & 127;
        const int n0  = (rem >> 2) * 64;
        const int d0  = (rem & 3) * 64;
        const int r   = t >> 2;                      // 0..63
        const int c4  = t & 3;                       // 0..3
        const float*    src = nodes   + ((size_t)b * N + n0) * D + d0;
        unsigned short* dst = nodesbf + ((size_t)b * N + n0) * D + d0;
        #pragma unroll
        for (int rep = 0; rep < 4; ++rep) {
            const int fc = c4 + rep * 4;
            float4 v = *(const float4*)(src + (size_t)r * D + fc * 4);
            ushort4 o;
            o.x = f2bf(v.x); o.y = f2bf(v.y); o.z = f2bf(v.z); o.w = f2bf(v.w);
            *(ushort4*)(dst + (size_t)r * D + fc * 4) = o;
            uchar4 o8;
            o8.x = f2fp8(v.x); o8.y = f2fp8(v.y); o8.z = f2fp8(v.z); o8.w = f2fp8(v.w);
            *(uchar4*)&T8[r][fc * 4] = o8;
        }
        __syncthreads();
        unsigned char* dstT = nodesT8 + ((size_t)b * D + d0) * N + n0;
        #pragma unroll
        for (int rep = 0; rep < 4; ++rep) {
            const int nc = c4 + rep * 4;
            uchar4 o;
            o.x = T8[nc * 4 + 0][r];
            o.y = T8[nc * 4 + 1][r];
            o.z = T8[nc * 4 + 2][r];
            o.w = T8[nc * 4 + 3][r];
            *(uchar4*)(dstT + (size_t)r * N + nc * 4) = o;
        }
    } else {
        // ---- weight cast ----
        const int i = (bx - 5120) * 256 + t;         // over L*D*D/4 = 32768
        float4 a = ((const float4*)W0_w)[i];
        ushort4 o0; o0.x = f2bf(a.x); o0.y = f2bf(a.y); o0.z = f2bf(a.z); o0.w = f2bf(a.w);
        ((ushort4*)W0b)[i] = o0;
        float4 c = ((const float4*)Wr_w)[i];
        ushort4 o1; o1.x = f2bf(c.x); o1.y = f2bf(c.y); o1.z = f2bf(c.z); o1.w = f2bf(c.w);
        ((ushort4*)Wrb)[i] = o1;
    }
}

// ---------------------------------------------------------------------------
// Kernel 2: big MFMA GEMM, MX-scaled fp8 (e4m3 x e4m3 -> fp32, unit scales),
// split-K=2:
//   ypart[s][b*N+m][d] = sum_{k in half s} adj8[b,m,k] * xT8[b,d,k]  (bf16 out)
//
// Tile 64(M) x 128(D), BK=64, 4 waves 2x2, each wave one 32x64 strip
// (2 x 32x32 MFMA tiles, K=64 per instruction). Grid = 1024 blocks = 4/CU.
//
// MFMA fragment (32x32x64_f8f6f4, 32 B/lane): row = lane&31,
// k = (lane>>5)*32 + j (family pattern, same as the verified 16x16x32 map).
//
// LDS layout per 32-row subtile (2048 B): [half h][lane][16 B] where
// LDS[sub][h][lane*16] = X[row = sub*32 + (lane&31)][k = (lane>>5)*32 + h*16 ..+16]
// -> gload16 dest is linear base + lane*16 (rule 21: linear dest, per-lane
//    pre-mapped global source), and fragment reads are linear lane*16
//    (conflict-free b128), second half at +1024.
// Scales = 0x7f (e8m0 exponent 127 = x1.0) -> bit-identical to plain fp8 MFMA.
// ---------------------------------------------------------------------------
__global__ __launch_bounds__(256)
void big_mfma_kernel(const unsigned char* __restrict__ adj8,   // [B][N][N] fp8
                     const unsigned char* __restrict__ xT8,    // [B][D][N] fp8
                     unsigned short* __restrict__ ypart) {     // [2][M][D] bf16
    __shared__ __align__(16) unsigned char As[2 * 2048];   // 4 KB  (64 rows x 64 k)
    __shared__ __align__(16) unsigned char Bs[4 * 2048];   // 8 KB  (128 rows x 64 k)

    const int z     = blockIdx.z;
    const int b     = z & 7;
    const int split = z >> 3;
    const int n0    = blockIdx.x * 128;   // over D
    const int m0    = blockIdx.y * 64;    // over N
    const int t     = threadIdx.x;
    const int w     = t >> 6;
    const int lane  = t & 63;
    const int r32   = lane & 31;
    const int h32   = lane >> 5;
    const int wr    = w & 1;              // wave row (0..1) -> 32-row strip
    const int wc    = w >> 1;             // wave col (0..1) -> 64-col strip
    const int kbase = split * (N / 2);

    const unsigned char* Ab = adj8 + (size_t)b * N * N + kbase;
    const unsigned char* Bb = xT8  + (size_t)b * D * N + kbase;

    // Staging assignment (12 gload16 / block / step, 3 per wave):
    //  wave w: A subtile (w>>1), half (w&1)   [1 gload]
    //          B subtile w, halves 0 and 1    [2 gloads]
    const unsigned char* gA =
        Ab + (size_t)(m0 + (w >> 1) * 32 + r32) * N + h32 * 32 + (w & 1) * 16;
    unsigned char* lA = &As[(w >> 1) * 2048 + (w & 1) * 1024];
    const unsigned char* gB =
        Bb + (size_t)(n0 + w * 32 + r32) * N + h32 * 32;
    unsigned char* lB0 = &Bs[w * 2048];
    unsigned char* lB1 = &Bs[w * 2048 + 1024];

    f32x16 acc[2];
    #pragma unroll
    for (int j = 0; j < 2; ++j)
        #pragma unroll
        for (int e = 0; e < 16; ++e) acc[j][e] = 0.f;

    const int la = lane * 16;

    for (int k0 = 0; k0 < N / 2; k0 += 64) {
        __syncthreads();
        gload16(gA + k0,      lA);
        gload16(gB + k0,      lB0);
        gload16(gB + k0 + 16, lB1);
        __syncthreads();

        // A fragment: rows wr*32 .. +32
        i32x4 alo = *(const i32x4*)&As[wr * 2048 + la];
        i32x4 ahi = *(const i32x4*)&As[wr * 2048 + 1024 + la];
        i32x8 af;
        af[0] = alo[0]; af[1] = alo[1]; af[2] = alo[2]; af[3] = alo[3];
        af[4] = ahi[0]; af[5] = ahi[1]; af[6] = ahi[2]; af[7] = ahi[3];

        #pragma unroll
        for (int j = 0; j < 2; ++j) {
            const int sb = wc * 2 + j;    // B subtile: cols (wc*64 + j*32) .. +32
            i32x4 blo = *(const i32x4*)&Bs[sb * 2048 + la];
            i32x4 bhi = *(const i32x4*)&Bs[sb * 2048 + 1024 + la];
            i32x8 bf;
            bf[0] = blo[0]; bf[1] = blo[1]; bf[2] = blo[2]; bf[3] = blo[3];
            bf[4] = bhi[0]; bf[5] = bhi[1]; bf[6] = bhi[2]; bf[7] = bhi[3];
            acc[j] = __builtin_amdgcn_mfma_scale_f32_32x32x64_f8f6f4(
                af, bf, acc[j],
                0 /*cbsz: A=fp8*/, 0 /*blgp: B=fp8*/,
                0, 0x7f7f7f7f /*scale A = 1.0*/,
                0, 0x7f7f7f7f /*scale B = 1.0*/);
        }
    }

    // Epilogue: 32x32 C/D layout col=lane&31, row=(r&3)+8*(r>>2)+4*(lane>>5)
    unsigned short* yb = ypart + ((size_t)split * M + (size_t)b * N) * D;
    #pragma unroll
    for (int j = 0; j < 2; ++j) {
        #pragma unroll
        for (int r = 0; r < 16; ++r) {
            const int row = (r & 3) + 8 * (r >> 2) + 4 * h32;
            const int m   = m0 + wr * 32 + row;
            const int d   = n0 + wc * 64 + j * 32 + r32;
            yb[(size_t)m * D + d] = f2bf(acc[j][r]);
        }
    }
}

// ---------------------------------------------------------------------------
// Kernel 3: small fused GEMM over concat-K (768 = y0|y1|x), bf16:
//   z[m,j] = sum_d (y0+y1)[m,d]*Wr[j,d] + sum_d x[m,d]*W0[j,d]
//   v = relu((z + b0[j] + br[j]*rowsum[m]) * rdenom[m])
//   non-final: xout[m][j]=bf16(v), xoutT8[b][j][n]=fp8(v)
//   final:     out[m][j] = nodes_f32[m][j] + v   (fp32)
// ---------------------------------------------------------------------------
__global__ __launch_bounds__(256)
void small_mfma_kernel(const unsigned short* __restrict__ y0,   // [M][D] bf16
                       const unsigned short* __restrict__ y1,   // [M][D] bf16
                       const unsigned short* __restrict__ x,    // [M][D] bf16
                       const unsigned short* __restrict__ Wrb,  // [D][D] bf16 (layer)
                       const unsigned short* __restrict__ W0b,  // [D][D] bf16 (layer)
                       const float* __restrict__ br,            // [D]
                       const float* __restrict__ b0,            // [D]
                       const float* __restrict__ rdenom,        // [M]
                       const float* __restrict__ rowsum,        // [M]
                       const float* __restrict__ nodesf,        // final only (fp32)
                       unsigned short* __restrict__ xout,       // non-final (bf16)
                       unsigned char* __restrict__ xoutT8,      // non-final (fp8 T)
                       float* __restrict__ out) {               // final only
    __shared__ __align__(16) unsigned short As[16 * 512];   // 16 KB
    __shared__ __align__(16) unsigned short Bs[8 * 512];    //  8 KB

    const int n0   = blockIdx.x * 64;    // over D (output feature)
    const int m0   = blockIdx.y * 128;   // over M
    const int t    = threadIdx.x;
    const int w    = t >> 6;
    const int lane = t & 63;
    const int lrow = lane & 15;
    const int lk   = (lane >> 4) * 8;

    const size_t aRow0 = (size_t)(m0 + (2 * w + 0) * 16 + lrow) * D + lk;
    const size_t aRow1 = (size_t)(m0 + (2 * w + 1) * 16 + lrow) * D + lk;
    const size_t bRow  = (size_t)(n0 + w * 16 + lrow) * D + lk;

    f32x4 acc[4][2];
    const f32x4 zero = {0.f, 0.f, 0.f, 0.f};
    #pragma unroll
    for (int i = 0; i < 4; ++i)
        #pragma unroll
        for (int j = 0; j < 2; ++j) acc[i][j] = zero;

    #pragma unroll
    for (int s = 0; s < 3; ++s) {
        const unsigned short* Asrc = (s == 0) ? y0 : (s == 1) ? y1 : x;
        const unsigned short* Bsrc = (s < 2) ? Wrb : W0b;
        #pragma unroll
        for (int kk = 0; kk < D; kk += 64) {
            __syncthreads();
            gload16(Asrc + aRow0 + kk,      &As[((2 * w + 0) * 2 + 0) * 512]);
            gload16(Asrc + aRow0 + kk + 32, &As[((2 * w + 0) * 2 + 1) * 512]);
            gload16(Asrc + aRow1 + kk,      &As[((2 * w + 1) * 2 + 0) * 512]);
            gload16(Asrc + aRow1 + kk + 32, &As[((2 * w + 1) * 2 + 1) * 512]);
            gload16(Bsrc + bRow + kk,       &Bs[(w * 2 + 0) * 512]);
            gload16(Bsrc + bRow + kk + 32,  &Bs[(w * 2 + 1) * 512]);
            __syncthreads();
            #pragma unroll
            for (int kc = 0; kc < 2; ++kc) {
                bf16x8 a[4], bb[2];
                #pragma unroll
                for (int i = 0; i < 4; ++i)
                    a[i] = *(const bf16x8*)&As[((((w & 1) * 4 + i) * 2) + kc) * 512 + lane * 8];
                #pragma unroll
                for (int j = 0; j < 2; ++j)
                    bb[j] = *(const bf16x8*)&Bs[((((w >> 1) * 2 + j) * 2) + kc) * 512 + lane * 8];
                #pragma unroll
                for (int i = 0; i < 4; ++i)
                    #pragma unroll
                    for (int j = 0; j < 2; ++j)
                        acc[i][j] = __builtin_amdgcn_mfma_f32_16x16x32_bf16(
                            a[i], bb[j], acc[i][j], 0, 0, 0);
            }
        }
    }

    const int col  = lane & 15;
    const int quad = lane >> 4;
    #pragma unroll
    for (int i = 0; i < 4; ++i) {
        const int mBase = m0 + (w & 1) * 64 + i * 16 + quad * 4;
        float rd[4], ss[4];
        #pragma unroll
        for (int r = 0; r < 4; ++r) {
            rd[r] = rdenom[mBase + r];
            ss[r] = rowsum[mBase + r];
        }
        #pragma unroll
        for (int j = 0; j < 2; ++j) {
            const int jj = n0 + (w >> 1) * 32 + j * 16 + col;
            const float bj = b0[jj];
            const float bv = br[jj];
            if (out) {
                #pragma unroll
                for (int r = 0; r < 4; ++r) {
                    const size_t idx = (size_t)(mBase + r) * D + jj;
                    float v = (acc[i][j][r] + bj + bv * ss[r]) * rd[r];
                    out[idx] = nodesf[idx] + fmaxf(v, 0.f);
                }
            } else {
                float v0 = fmaxf((acc[i][j][0] + bj + bv * ss[0]) * rd[0], 0.f);
                float v1 = fmaxf((acc[i][j][1] + bj + bv * ss[1]) * rd[1], 0.f);
                float v2 = fmaxf((acc[i][j][2] + bj + bv * ss[2]) * rd[2], 0.f);
                float v3 = fmaxf((acc[i][j][3] + bj + bv * ss[3]) * rd[3], 0.f);
                xout[(size_t)(mBase + 0) * D + jj] = f2bf(v0);
                xout[(size_t)(mBase + 1) * D + jj] = f2bf(v1);
                xout[(size_t)(mBase + 2) * D + jj] = f2bf(v2);
                xout[(size_t)(mBase + 3) * D + jj] = f2bf(v3);
                // transposed fp8 for next layer's big GEMM B-operand
                uchar4 o8;
                o8.x = f2fp8(v0); o8.y = f2fp8(v1); o8.z = f2fp8(v2); o8.w = f2fp8(v3);
                const int bb_  = m0 >> 11;           // batch (tile never crosses)
                const int nloc = mBase & (N - 1);
                *(uchar4*)&xoutT8[((size_t)bb_ * D + jj) * N + nloc] = o8;
            }
        }
    }
}

// ---------------------------------------------------------------------------
extern "C" void kernel_launch(void* const* d_in, const int* in_sizes, int n_in,
                              void* d_out, int out_size, void* d_ws, size_t ws_size,
                              hipStream_t stream) {
    const float* nodes = (const float*)d_in[0];   // [B,N,D]
    const float* adj   = (const float*)d_in[1];   // [B,N,N]
    const float* W0_w  = (const float*)d_in[2];   // [L,D,D]
    const float* W0_b  = (const float*)d_in[3];   // [L,D]
    const float* Wr_w  = (const float*)d_in[4];   // [L,D,D]
    const float* Wr_b  = (const float*)d_in[5];   // [L,D]
    float* out = (float*)d_out;

    unsigned char*  adj8    = (unsigned char*)d_ws;           // B*N*N fp8 (33.5 MB)
    unsigned char*  xT8     = adj8 + (size_t)B * N * N;       // [B][D][N] fp8 (4.2 MB)
    unsigned short* nodesbf = (unsigned short*)(xT8 + (size_t)B * D * N);  // [M][D] bf16
    unsigned short* ybuf    = nodesbf + (size_t)M * D;        // [2][M][D] bf16
    unsigned short* x1      = ybuf + (size_t)2 * M * D;       // [M][D] bf16
    unsigned short* Wrb     = x1 + (size_t)M * D;             // L*D*D bf16
    unsigned short* W0b     = Wrb + (size_t)L * D * D;        // L*D*D bf16
    float* rdenom = (float*)(W0b + (size_t)L * D * D);        // M
    float* rowsum = rdenom + M;                               // M

    prep_kernel<<<dim3(5248), 256, 0, stream>>>(
        adj, nodes, W0_w, Wr_w,
        adj8, rdenom, rowsum, nodesbf, xT8, W0b, Wrb);

    unsigned short* y0 = ybuf;
    unsigned short* y1 = ybuf + (size_t)M * D;

    // layer 0
    big_mfma_kernel<<<dim3(D / 128, N / 64, 2 * B), 256, 0, stream>>>(adj8, xT8, ybuf);
    small_mfma_kernel<<<dim3(D / 64, M / 128), 256, 0, stream>>>(
        y0, y1, nodesbf, Wrb, W0b, Wr_b, W0_b, rdenom, rowsum,
        nullptr, x1, xT8, nullptr);

    // layer 1
    big_mfma_kernel<<<dim3(D / 128, N / 64, 2 * B), 256, 0, stream>>>(adj8, xT8, ybuf);
    small_mfma_kernel<<<dim3(D / 64, M / 128), 256, 0, stream>>>(
        y0, y1, x1, Wrb + D * D, W0b + D * D, Wr_b + D, W0_b + D, rdenom, rowsum,
        nodes, nullptr, nullptr, out);
}